// Round 8
// baseline (330.155 us; speedup 1.0000x reference)
//
#include <hip/hip_runtime.h>
#include <hip/hip_fp16.h>
#include <math.h>

// 2-layer GAT. N=50000, E=800000 (+N self loops), F=128, H=8, C=32, NCLS=16.
// R24: R23's atomic CSR build lost 50us to OCCUPANCY, not atomics: scatter ran
// 256 blocks = 4 waves/CU, 13 serial dependent chains/thread. Fix: full-TLP
// counting sort -- k_deg and k_scatter at 4 edges/thread over resident grids
// (~832 blocks, 13 waves/CU, single pass); k_fin folds bsum-prefix into
// rowfin BEFORE scatter so the per-edge path is rowfin[d] + atomicAdd(cur[d])
// + store (3 ops, 850K independent chains). R23 already proved atomic-order
// scatter is numerically identical (absmax 2^-9 bit-stable). agg1 stays v2
// (closed at ~73us = VMEM delivery floor, 435MB compulsory @ ~6TB/s).
//   K1 prep(Wt,deg=1,cur=0) | K2 deg | K3 scan+gemm1 | K4 fin | K5 scatter
//   | K6 agg1 | K7 gemm2 | K8 agg2

typedef _Float16 f16x8 __attribute__((ext_vector_type(8)));
typedef _Float16 f16x4 __attribute__((ext_vector_type(4)));
typedef float    f32x4 __attribute__((ext_vector_type(4)));

__device__ __forceinline__ float lrelu(float v){ return v > 0.f ? v : 0.2f*v; }

// ---------------- K1: weight prep + deg=1 (self loops) + cur=0 ----------------
__global__ __launch_bounds__(256) void k_prep(const float* __restrict__ W1,
    _Float16* __restrict__ W1t, const float* __restrict__ W2,
    _Float16* __restrict__ W2t, int* __restrict__ deg, int* __restrict__ cur, int N)
{
  int b = blockIdx.x, t = threadIdx.x;
  if (b < 128){
    W1t[t*128 + b] = (_Float16)W1[b*256 + t];
  } else if (b == 128){
    for (int i=t; i<4096; i+=256){ int k=i&255, j=i>>8; W2t[j*256+k] = (_Float16)W2[k*16+j]; }
  } else {
    int i = (b-129)*1024 + t*4;
    if (i+0 < N){ deg[i+0] = 1; cur[i+0] = 0; }
    if (i+1 < N){ deg[i+1] = 1; cur[i+1] = 0; }
    if (i+2 < N){ deg[i+2] = 1; cur[i+2] = 0; }
    if (i+3 < N){ deg[i+3] = 1; cur[i+3] = 0; }
  }
}

// ---------------- K2: degree count, 4 edges/thread, resident grid ----------------
__global__ __launch_bounds__(256) void k_deg(const int* __restrict__ dstv,
    int* __restrict__ deg, int E)
{
  int e = blockIdx.x*1024 + threadIdx.x*4;
  if (e+3 < E){
    int4 d = *(const int4*)(dstv + e);
    atomicAdd(&deg[d.x], 1);
    atomicAdd(&deg[d.y], 1);
    atomicAdd(&deg[d.z], 1);
    atomicAdd(&deg[d.w], 1);
  } else {
    for (int i=e; i<E; ++i) atomicAdd(&deg[dstv[i]], 1);
  }
}

// ---------------- K3: scan(deg) (blocks 0..SB-1) + GEMM1 tiles ----------------
__global__ __launch_bounds__(256) void k_g1scan(const float* __restrict__ x,
    const _Float16* __restrict__ W1t, const float* __restrict__ as1,
    const float* __restrict__ ad1, _Float16* __restrict__ h1,
    float* __restrict__ a_src1, float* __restrict__ a_dst1,
    const int* __restrict__ deg, int* __restrict__ rowptr,
    int* __restrict__ bsum, int N, int SB)
{
  __shared__ char smem[33792];
  int t = threadIdx.x;
  int b = blockIdx.x;

  if (b < SB){
    // ---- block-local exclusive scan over deg (N%4==0 -> int4 safe) ----
    int* lds = (int*)smem;
    int base = b*1024 + t*4;
    int r0=0, r1=0, r2=0, r3=0;
    if (base < N){
      int4 dv = *(const int4*)(deg + base);
      r0=dv.x; r1=dv.y; r2=dv.z; r3=dv.w;
    }
    int tot = r0+r1+r2+r3;
    lds[t] = tot; __syncthreads();
    for (int off=1; off<256; off<<=1){
      int add = (t>=off)?lds[t-off]:0;
      __syncthreads();
      lds[t] += add;
      __syncthreads();
    }
    int excl = lds[t] - tot;
    if (t==255) bsum[b] = lds[t];
    int run = excl;
    if (base+0<N){ rowptr[base+0]=run; run+=r0; }
    if (base+1<N){ rowptr[base+1]=run; run+=r1; }
    if (base+2<N){ rowptr[base+2]=run; run+=r2; }
    if (base+3<N){ rowptr[base+3]=run; }
    return;
  }

  // ---- GEMM1 (MFMA): h1 = x @ W1 -> fp16 (node-major), + a_src1/a_dst1 ----
  _Float16* As = (_Float16*)smem;           // [64 rows][136 halves] (272 B stride)
  int n0 = (b - SB)*64;

  #pragma unroll
  for (int it=0; it<8; ++it){
    int c = it*256 + t;
    int row = c >> 5;
    int c4  = c & 31;
    int gr = n0 + row; if (gr > N-1) gr = N-1;
    float4 v = *(const float4*)(x + (size_t)gr*128 + c4*4);
    _Float16* dp = As + row*136 + c4*4;
    dp[0]=(_Float16)v.x; dp[1]=(_Float16)v.y; dp[2]=(_Float16)v.z; dp[3]=(_Float16)v.w;
  }
  __syncthreads();

  int wv = t>>6, lane = t&63;
  int m = lane&15, q = lane>>4;
  int r0w = wv*16;

  f16x8 afr[4];
  #pragma unroll
  for (int ks=0; ks<4; ++ks)
    afr[ks] = *(const f16x8*)((const char*)As + (r0w+m)*272 + ks*64 + q*16);

  f32x4 acc[16];
  #pragma unroll
  for (int ct=0; ct<16; ++ct) acc[ct] = (f32x4){0.f,0.f,0.f,0.f};

  const char* bbase = (const char*)W1t;
  #pragma unroll
  for (int ct=0; ct<16; ++ct){
    const char* bp = bbase + (ct*16 + m)*256 + q*16;
    f16x8 b0 = *(const f16x8*)(bp);
    f16x8 b1 = *(const f16x8*)(bp+64);
    f16x8 b2 = *(const f16x8*)(bp+128);
    f16x8 b3 = *(const f16x8*)(bp+192);
    acc[ct] = __builtin_amdgcn_mfma_f32_16x16x32_f16(afr[0], b0, acc[ct],0,0,0);
    acc[ct] = __builtin_amdgcn_mfma_f32_16x16x32_f16(afr[1], b1, acc[ct],0,0,0);
    acc[ct] = __builtin_amdgcn_mfma_f32_16x16x32_f16(afr[2], b2, acc[ct],0,0,0);
    acc[ct] = __builtin_amdgcn_mfma_f32_16x16x32_f16(afr[3], b3, acc[ct],0,0,0);
  }
  __syncthreads();

  _Float16* Hs = (_Float16*)smem;           // [64][264] halves, 528B stride
  #pragma unroll
  for (int ct=0; ct<16; ++ct){
    #pragma unroll
    for (int r=0; r<4; ++r)
      Hs[(size_t)(r0w + q*4 + r)*264 + ct*16 + m] = (_Float16)acc[ct][r];
  }
  __syncthreads();

  for (int r=0; r<16; ++r){
    int grow = n0 + r0w + r;
    if (grow < N){
      uint2 v = *(const uint2*)((const char*)Hs + (size_t)(r0w+r)*528 + lane*8);
      *(uint2*)((char*)h1 + (size_t)grow*512 + lane*8) = v;
    }
  }

  #pragma unroll
  for (int p=t; p<512; p+=256){
    int row = p>>3, hd = p&7;
    int grow = n0 + row;
    if (grow < N){
      const _Float16* hr = Hs + (size_t)row*264 + hd*32;
      float sa=0.f, sd=0.f;
      #pragma unroll
      for (int c=0; c<32; ++c){
        float hv = (float)hr[c];
        sa += hv * as1[hd*32+c];
        sd += hv * ad1[hd*32+c];
      }
      a_src1[(size_t)grow*8+hd] = sa;
      a_dst1[(size_t)grow*8+hd] = sd;
    }
  }
}

// ---------------- K4: finalize rowfin = rowptr + prefix(bsum) ----------------
__global__ __launch_bounds__(256) void k_fin(const int* __restrict__ rowptr,
    const int* __restrict__ bsum, int* __restrict__ rowfin, int N, int SB, int Etot)
{
  __shared__ int ps[64];
  int b = blockIdx.x, t = threadIdx.x;
  if (t < 64) ps[t] = (t < SB) ? bsum[t] : 0;
  __syncthreads();
  for (int off=1; off<64; off<<=1){
    int add = (t < 64 && t >= off) ? ps[t-off] : 0;
    __syncthreads();
    if (t < 64) ps[t] += add;
    __syncthreads();
  }
  int pref = (b == 0) ? 0 : ps[b-1];        // exclusive prefix for this block
  int i = b*1024 + t*4;
  if (i+0 < N) rowfin[i+0] = rowptr[i+0] + pref;
  if (i+1 < N) rowfin[i+1] = rowptr[i+1] + pref;
  if (i+2 < N) rowfin[i+2] = rowptr[i+2] + pref;
  if (i+3 < N) rowfin[i+3] = rowptr[i+3] + pref;
  if (b==0 && t==0) rowfin[N] = Etot;
}

// ---------------- K5: scatter, 4 edges/thread, resident grid ----------------
__global__ __launch_bounds__(256) void k_scatter(const int* __restrict__ srcv,
    const int* __restrict__ dstv, const int* __restrict__ rowfin,
    int* __restrict__ cur, int* __restrict__ csr_src, int E, int Etot)
{
  int e0 = blockIdx.x*1024 + threadIdx.x*4;
  #pragma unroll
  for (int u=0; u<4; ++u){
    int e = e0 + u;
    if (e < Etot){
      int d, s;
      if (e < E){ d = dstv[e]; s = srcv[e]; } else { d = e - E; s = d; }
      int o = atomicAdd(&cur[d], 1);
      csr_src[rowfin[d] + o] = s;
    }
  }
}

// ---------------- K6: Layer-1 aggregation v2 (two-phase, 16-deep scalar-addr gathers) ----------------
// Verified ~73us; at the ~6TB/s VGPR-delivery floor (bytes compulsory).
__global__ __launch_bounds__(256) void k_agg1(const __half* __restrict__ h1,
    const float* __restrict__ a_src1, const float* __restrict__ a_dst1,
    const int* __restrict__ rowfin, const int* __restrict__ csr_src,
    const float* __restrict__ bias1, _Float16* __restrict__ h2f, int N)
{
  __shared__ float wlds[4*640];             // 4 waves x (64 edges x 9 floats, pad)
  int wave = (blockIdx.x*blockDim.x + threadIdx.x) >> 6;
  if (wave >= N) return;
  int lane = threadIdx.x & 63;
  int wid  = (threadIdx.x >> 6) & 3;
  int head = lane >> 3;
  float* wb = wlds + wid*640;
  const float* wcol = wb + head;            // + j*9 per edge

  int beg = rowfin[wave], end = rowfin[wave+1];
  int deg = end - beg;
  const float4 av0 = *(const float4*)(a_dst1 + (size_t)wave*8);
  const float4 av1 = *(const float4*)(a_dst1 + (size_t)wave*8 + 4);

  float4 acc = make_float4(0.f,0.f,0.f,0.f);
  float wsum = 0.f;

  for (int kb = 0; kb < deg; kb += 64){
    int nb = deg - kb; if (nb > 64) nb = 64;

    // ---- phase A: per-lane edge weights for all 8 heads ----
    int sl = 0;
    if (lane < nb) sl = csr_src[beg + kb + lane];
    const float4* ep = (const float4*)(a_src1 + (size_t)sl*8);
    float4 e0 = ep[0];
    float4 e1 = ep[1];
    float w0=0.f,w1=0.f,w2=0.f,w3=0.f,w4=0.f,w5=0.f,w6=0.f,w7=0.f;
    if (lane < nb){
      w0 = __expf(lrelu(e0.x + av0.x));
      w1 = __expf(lrelu(e0.y + av0.y));
      w2 = __expf(lrelu(e0.z + av0.z));
      w3 = __expf(lrelu(e0.w + av0.w));
      w4 = __expf(lrelu(e1.x + av1.x));
      w5 = __expf(lrelu(e1.y + av1.y));
      w6 = __expf(lrelu(e1.z + av1.z));
      w7 = __expf(lrelu(e1.w + av1.w));
    }
    float* wr = wb + lane*9;
    wr[0]=w0; wr[1]=w1; wr[2]=w2; wr[3]=w3;
    wr[4]=w4; wr[5]=w5; wr[6]=w6; wr[7]=w7;
    // no barrier: region is per-wave private; same-wave DS ops are ordered.

    // ---- phase B: 16-deep gather batches ----
    int nb16 = nb & ~15;
    int j = 0;
    for (; j < nb16; j += 16){
      uint2 p[16];
      #pragma unroll
      for (int u=0;u<16;++u){
        int s = __builtin_amdgcn_readlane(sl, j+u);       // scalar row base
        p[u] = *(const uint2*)((const char*)h1 + (size_t)s*512 + lane*8);
      }
      float wv[16];
      #pragma unroll
      for (int u=0;u<16;++u) wv[u] = wcol[(j+u)*9];
      #pragma unroll
      for (int u=0;u<16;++u){
        wsum += wv[u];
        const __half2* qq = (const __half2*)&p[u];
        float2 f0 = __half22float2(qq[0]);
        float2 f1 = __half22float2(qq[1]);
        acc.x += wv[u]*f0.x; acc.y += wv[u]*f0.y;
        acc.z += wv[u]*f1.x; acc.w += wv[u]*f1.y;
      }
    }
    // remainder: padded 4-batches; padded slots have w==0 (exact no-op)
    for (; j < nb; j += 4){
      uint2 p[4]; float wv[4];
      #pragma unroll
      for (int u=0;u<4;++u){
        int jj = j+u;
        int s = __builtin_amdgcn_readlane(sl, jj & 63);
        p[u] = *(const uint2*)((const char*)h1 + (size_t)s*512 + lane*8);
        wv[u] = (jj < 64) ? wcol[jj*9] : 0.f;
      }
      #pragma unroll
      for (int u=0;u<4;++u){
        wsum += wv[u];
        const __half2* qq = (const __half2*)&p[u];
        float2 f0 = __half22float2(qq[0]);
        float2 f1 = __half22float2(qq[1]);
        acc.x += wv[u]*f0.x; acc.y += wv[u]*f0.y;
        acc.z += wv[u]*f1.x; acc.w += wv[u]*f1.y;
      }
    }
  }

  float dinv = 1.f/(wsum + 1e-16f);
  const float4 bv = *(const float4*)(bias1 + lane*4);
  float4 o;
  o.x = acc.x*dinv + bv.x;
  o.y = acc.y*dinv + bv.y;
  o.z = acc.z*dinv + bv.z;
  o.w = acc.w*dinv + bv.w;
  o.x = o.x > 0.f ? o.x : __expf(o.x)-1.f;
  o.y = o.y > 0.f ? o.y : __expf(o.y)-1.f;
  o.z = o.z > 0.f ? o.z : __expf(o.z)-1.f;
  o.w = o.w > 0.f ? o.w : __expf(o.w)-1.f;
  f16x4 ov = { (_Float16)o.x, (_Float16)o.y, (_Float16)o.z, (_Float16)o.w };
  *(f16x4*)(h2f + (size_t)wave*256 + lane*4) = ov;
}

// ---------------- K7: GEMM2 (MFMA): hb(fp16) = h2f @ W2, + a_src2/a_dst2 ----------------
__global__ __launch_bounds__(256) void k_gemm2(const _Float16* __restrict__ h2f,
    const _Float16* __restrict__ W2t, const float* __restrict__ as2, const float* __restrict__ ad2,
    _Float16* __restrict__ hbh, float* __restrict__ a_src2, float* __restrict__ a_dst2, int N)
{
  int t = threadIdx.x, wv = t>>6, lane = t&63;
  int col = lane&15, q = lane>>4;
  int n0 = blockIdx.x*64 + wv*16;
  int am = n0 + col; if (am > N-1) am = N-1;

  const _Float16* arow = h2f + (size_t)am*256 + q*8;
  const _Float16* brow = W2t + (size_t)col*256 + q*8;
  f32x4 acc = (f32x4){0.f,0.f,0.f,0.f};
  #pragma unroll
  for (int ks=0; ks<8; ++ks){
    f16x8 a = *(const f16x8*)(arow + ks*32);
    f16x8 b = *(const f16x8*)(brow + ks*32);
    acc = __builtin_amdgcn_mfma_f32_16x16x32_f16(a, b, acc, 0,0,0);
  }

  float vs = as2[col], vd = ad2[col];
  #pragma unroll
  for (int r=0; r<4; ++r){
    int n = n0 + q*4 + r;
    float v = acc[r];
    float pa = v*vs, pd = v*vd;
    #pragma unroll
    for (int msk=8; msk>=1; msk>>=1){ pa += __shfl_xor(pa,msk); pd += __shfl_xor(pd,msk); }
    if (n < N){
      hbh[(size_t)n*16 + col] = (_Float16)v;
      if (col==0){ a_src2[n] = pa; a_dst2[n] = pd; }
    }
  }
}

// ---------------- K8: Layer-2 aggregation: wave per dst, 4 edge-groups x 16 ch ----------------
__global__ __launch_bounds__(256) void k_agg2(const __half* __restrict__ hbh,
    const float* __restrict__ a_src2, const float* __restrict__ a_dst2,
    const int* __restrict__ rowfin, const int* __restrict__ csr_src,
    const float* __restrict__ bias2, float* __restrict__ out, int N)
{
  int wave = (blockIdx.x*blockDim.x + threadIdx.x) >> 6;
  if (wave >= N) return;
  int lane = threadIdx.x & 63;
  int eg   = lane >> 4;
  int ch   = lane & 15;
  float ad = a_dst2[wave];
  int beg = rowfin[wave], end = rowfin[wave+1];
  float acc = 0.f, wsum = 0.f;
  int i = beg + eg;
  for (; i+4 < end; i+=8){
    int s0 = csr_src[i], s1 = csr_src[i+4];
    float e0 = a_src2[s0], e1 = a_src2[s1];
    float h0 = __half2float(hbh[(size_t)s0*16 + ch]);
    float h1v = __half2float(hbh[(size_t)s1*16 + ch]);
    float w0 = __expf(lrelu(e0 + ad)), w1 = __expf(lrelu(e1 + ad));
    wsum += w0 + w1;
    acc += w0*h0 + w1*h1v;
  }
  for (; i<end; i+=4){
    int s = csr_src[i];
    float w = __expf(lrelu(a_src2[s] + ad));
    wsum += w;
    acc += w * __half2float(hbh[(size_t)s*16 + ch]);
  }
  acc  += __shfl_xor(acc, 16);  acc  += __shfl_xor(acc, 32);
  wsum += __shfl_xor(wsum, 16); wsum += __shfl_xor(wsum, 32);
  if (eg == 0)
    out[(size_t)wave*16 + ch] = acc/(wsum + 1e-16f) + bias2[ch];
}

extern "C" void kernel_launch(void* const* d_in, const int* in_sizes, int n_in,
                              void* d_out, int out_size, void* d_ws, size_t ws_size,
                              hipStream_t stream)
{
  const float* x   = (const float*)d_in[0];
  const int*   ei  = (const int*)  d_in[1];
  const float* W1  = (const float*)d_in[2];
  const float* as1 = (const float*)d_in[3];
  const float* ad1 = (const float*)d_in[4];
  const float* b1  = (const float*)d_in[5];
  const float* W2  = (const float*)d_in[6];
  const float* as2 = (const float*)d_in[7];
  const float* ad2 = (const float*)d_in[8];
  const float* b2  = (const float*)d_in[9];
  float* out = (float*)d_out;

  const int N    = in_sizes[0] / 128;       // 50000
  const int E    = in_sizes[1] / 2;         // 800000
  const int Etot = E + N;
  const int* srcv = ei;
  const int* dstv = ei + E;
  const int SB    = (N + 1023) / 1024;      // 49 scan blocks
  const int TN    = (N + 63) / 64;          // 782 gemm1 tiles
  const int ZB    = (N + 1023) / 1024;      // 49 init blocks
  const int DB    = (E + 1023) / 1024;      // 782 deg blocks (4 edges/thread)
  const int XB    = (Etot + 1023) / 1024;   // 831 scatter blocks (4 edges/thread)

  char* p = (char*)d_ws;
  auto alloc = [&](size_t bytes)->void* {
    void* r = (void*)p;
    p += (bytes + 255) & ~((size_t)255);
    return r;
  };
  _Float16* h1   = (_Float16*)alloc((size_t)N*256*sizeof(_Float16));   // node-major [N][256]
  _Float16* W1t  = (_Float16*)alloc((size_t)256*128*sizeof(_Float16));
  _Float16* h2f  = (_Float16*)alloc((size_t)N*256*sizeof(_Float16));
  _Float16* W2t  = (_Float16*)alloc((size_t)16*256*sizeof(_Float16));
  _Float16* hbh  = (_Float16*)alloc((size_t)N*16*sizeof(_Float16));
  float* a_src1  = (float*)alloc((size_t)N*8*sizeof(float));
  float* a_dst1  = (float*)alloc((size_t)N*8*sizeof(float));
  float* a_src2  = (float*)alloc((size_t)N*sizeof(float));
  float* a_dst2  = (float*)alloc((size_t)N*sizeof(float));
  int*   rowptr  = (int*)alloc((size_t)(N+1)*sizeof(int));
  int*   rowfin  = (int*)alloc((size_t)(N+1)*sizeof(int));
  int*   bsum    = (int*)alloc(256*sizeof(int));
  int*   deg     = (int*)alloc((size_t)N*sizeof(int));
  int*   cur     = (int*)alloc((size_t)N*sizeof(int));
  int*   csr_src = (int*)alloc((size_t)Etot*sizeof(int));

  // K1: W transposes + deg=1 (covers self loops) + cur=0
  k_prep<<<dim3(129 + ZB), dim3(256), 0, stream>>>(W1, W1t, W2, W2t, deg, cur, N);
  // K2: degree histogram via global atomics (deg is 200KB, L2-resident)
  k_deg<<<dim3(DB), dim3(256), 0, stream>>>(dstv, deg, E);
  // K3: scan(deg) (blocks 0..SB-1) + gemm1 (blocks SB..SB+TN-1)
  k_g1scan<<<dim3(SB + TN), dim3(256), 0, stream>>>(x, W1t, as1, ad1, h1,
      a_src1, a_dst1, deg, rowptr, bsum, N, SB);
  // K4: finalize rowfin (rowptr + prefix(bsum)) BEFORE scatter
  k_fin<<<dim3(SB), dim3(256), 0, stream>>>(rowptr, bsum, rowfin, N, SB, Etot);
  // K5: scatter via global cursor atomics, full-TLP grid
  k_scatter<<<dim3(XB), dim3(256), 0, stream>>>(srcv, dstv, rowfin, cur, csr_src, E, Etot);
  // K6: agg1 (v2, verified ~73us roofline)
  k_agg1<<<dim3((N + 3)/4), dim3(256), 0, stream>>>((const __half*)h1, a_src1, a_dst1,
      rowfin, csr_src, b1, h2f, N);
  // K7: gemm2 (fp16 hb)
  k_gemm2<<<dim3((N + 63)/64), dim3(256), 0, stream>>>(h2f, W2t, as2, ad2, hbh, a_src2, a_dst2, N);
  // K8: agg2
  k_agg2<<<dim3((N + 3)/4), dim3(256), 0, stream>>>((const __half*)hbh, a_src2, a_dst2,
      rowfin, csr_src, b2, out, N);
}

// Round 9
// 270.920 us; speedup vs baseline: 1.2186x; 1.2186x over previous
//
#include <hip/hip_runtime.h>
#include <hip/hip_fp16.h>
#include <math.h>

// 2-layer GAT. N=50000, E=800000 (+N self loops), F=128, H=8, C=32, NCLS=16.
// R25: atomic CSR build CLOSED (R23 low-TLP +50us, R24 high-TLP +59us --
// device-scope RMW serializes at the cross-XCD coherence point regardless of
// occupancy). R18 hist/scanAB/scatter3 build restored verbatim. This round
// banks static op-count cuts in the latency-exposed build kernels (~1.5
// blocks/CU at 50KB LDS): (1) int4 LDS zero/copy in hist+scatter (98->26
// word-ops/thread); (2) gemm1 staging packs f16x4 -> 1 ds_write_b64 (was 4
// b16); (3) a_src/a_dst epilogue reads Hs via 4 ds_read_b128 (was 32
// ds_read_u16). Byte-exact math. agg1 stays v2 (closed: 73us = 94-97% of
// 6.29TB/s delivery ceiling on 435MB compulsory).
//   K1 histW | K2 scanAB+gemm1 | K3 scatter3+rowfin | K4 agg1 | K5 gemm2 | K6 agg2

#define NC    128          // edge chunks
#define NBK   256          // hist/scatter blocks = NC * 2 halves
#define NBINS 50000
#define HBINS 25000        // bins per half
#define NWH   12500        // packed u32 words per half (2 bins each)

typedef _Float16 f16x8 __attribute__((ext_vector_type(8)));
typedef _Float16 f16x4 __attribute__((ext_vector_type(4)));
typedef float    f32x4 __attribute__((ext_vector_type(4)));

__device__ __forceinline__ float lrelu(float v){ return v > 0.f ? v : 0.2f*v; }

// ---------------- K1: hist (packed u16, chunk x half) + weight prep ----------------
__global__ __launch_bounds__(256) void k_histW(const int* __restrict__ dstv,
    unsigned int* __restrict__ partial, int E, int Etot, int chunk,
    const float* __restrict__ W1, _Float16* __restrict__ W1t,
    const float* __restrict__ W2, _Float16* __restrict__ W2t)
{
  int b = blockIdx.x, t = threadIdx.x;
  if (b >= NBK){
    int b2 = b - NBK;
    if (b2 < 128){
      W1t[t*128 + b2] = (_Float16)W1[b2*256 + t];
    } else {
      for (int i=t; i<4096; i+=256){ int k=i&255, j=i>>8; W2t[j*256+k] = (_Float16)W2[k*16+j]; }
    }
    return;
  }
  __shared__ __align__(16) unsigned int cnt[NWH];   // 50 KB
  int c = b >> 1, half = b & 1, lo = half*HBINS;
  {
    int4* c4 = (int4*)cnt;
    for (int i=t; i<NWH/4; i+=256) c4[i] = make_int4(0,0,0,0);
  }
  __syncthreads();
  int e0 = c*chunk, e1 = e0+chunk; if (e1 > Etot) e1 = Etot;
  int e = e0 + t;
  for (; e + 768 < e1; e += 1024){
    int ea=e, eb=e+256, ec=e+512, ed=e+768;
    int d0 = (ea<E)?dstv[ea]:(ea-E);
    int d1 = (eb<E)?dstv[eb]:(eb-E);
    int d2 = (ec<E)?dstv[ec]:(ec-E);
    int d3 = (ed<E)?dstv[ed]:(ed-E);
    int r0=d0-lo, r1=d1-lo, r2=d2-lo, r3=d3-lo;
    if (r0>=0 && r0<HBINS) atomicAdd(&cnt[r0>>1], (r0&1)?65536u:1u);
    if (r1>=0 && r1<HBINS) atomicAdd(&cnt[r1>>1], (r1&1)?65536u:1u);
    if (r2>=0 && r2<HBINS) atomicAdd(&cnt[r2>>1], (r2&1)?65536u:1u);
    if (r3>=0 && r3<HBINS) atomicAdd(&cnt[r3>>1], (r3&1)?65536u:1u);
  }
  for (; e < e1; e += 256){
    int d = (e<E)?dstv[e]:(e-E);
    int r = d - lo;
    if (r>=0 && r<HBINS) atomicAdd(&cnt[r>>1], (r&1)?65536u:1u);
  }
  __syncthreads();
  unsigned int* dp = partial + (size_t)c*HBINS + (size_t)half*NWH;
  {
    int4* d4 = (int4*)dp;
    const int4* c4 = (const int4*)cnt;
    for (int i=t; i<NWH/4; i+=256) d4[i] = c4[i];
  }
}

// ---------------- K2: scanAB (blocks 0..SB-1, batched prefetch) + GEMM1 tiles ----------------
__global__ __launch_bounds__(256) void k_g1scan(const float* __restrict__ x,
    const _Float16* __restrict__ W1t, const float* __restrict__ as1,
    const float* __restrict__ ad1, _Float16* __restrict__ h1,
    float* __restrict__ a_src1, float* __restrict__ a_dst1,
    unsigned long long* __restrict__ partial, int* __restrict__ rowptr,
    int* __restrict__ bsum, int N, int SB)
{
  __shared__ char smem[33792];
  int t = threadIdx.x;
  int b = blockIdx.x;

  if (b < SB){
    // ---- scanAB with explicit 16-deep load batching (breaks latency chain) ----
    int* lds = (int*)smem;
    int base = b*1024 + t*4;
    int r0=0, r1=0, r2=0, r3=0;
    if (base < N){
      unsigned long long* P = partial + (base >> 2);
      for (int cc0=0; cc0<NC; cc0+=16){
        unsigned long long v[16];
        #pragma unroll
        for (int j=0;j<16;++j) v[j] = P[(size_t)(cc0+j)*12500];   // 16 loads in flight
        #pragma unroll
        for (int j=0;j<16;++j){
          unsigned long long pref =  (unsigned long long)(r0 & 0xffff)
            | ((unsigned long long)(r1 & 0xffff) << 16)
            | ((unsigned long long)(r2 & 0xffff) << 32)
            | ((unsigned long long)(r3 & 0xffff) << 48);
          P[(size_t)(cc0+j)*12500] = pref;
          r0 += (int)( v[j]        & 0xffff);
          r1 += (int)((v[j] >> 16) & 0xffff);
          r2 += (int)((v[j] >> 32) & 0xffff);
          r3 += (int)((v[j] >> 48) & 0xffff);
        }
      }
    }
    int tot = r0+r1+r2+r3;
    lds[t] = tot; __syncthreads();
    for (int off=1; off<256; off<<=1){
      int add = (t>=off)?lds[t-off]:0;
      __syncthreads();
      lds[t] += add;
      __syncthreads();
    }
    int excl = lds[t] - tot;
    if (t==255) bsum[b] = lds[t];
    int run = excl;
    if (base+0<N){ rowptr[base+0]=run; run+=r0; }
    if (base+1<N){ rowptr[base+1]=run; run+=r1; }
    if (base+2<N){ rowptr[base+2]=run; run+=r2; }
    if (base+3<N){ rowptr[base+3]=run; }
    return;
  }

  // ---- GEMM1 (MFMA): h1 = x @ W1 -> fp16, + a_src1/a_dst1 ----
  _Float16* As = (_Float16*)smem;           // [64 rows][136 halves] (272 B stride)
  int n0 = (b - SB)*64;

  #pragma unroll
  for (int it=0; it<8; ++it){
    int c = it*256 + t;
    int row = c >> 5;
    int c4  = c & 31;
    int gr = n0 + row; if (gr > N-1) gr = N-1;
    float4 v = *(const float4*)(x + (size_t)gr*128 + c4*4);
    f16x4 hv = { (_Float16)v.x, (_Float16)v.y, (_Float16)v.z, (_Float16)v.w };
    *(f16x4*)(As + row*136 + c4*4) = hv;    // 1 ds_write_b64 (was 4 b16)
  }
  __syncthreads();

  int wv = t>>6, lane = t&63;
  int m = lane&15, q = lane>>4;
  int r0w = wv*16;

  f16x8 afr[4];
  #pragma unroll
  for (int ks=0; ks<4; ++ks)
    afr[ks] = *(const f16x8*)((const char*)As + (r0w+m)*272 + ks*64 + q*16);

  f32x4 acc[16];
  #pragma unroll
  for (int ct=0; ct<16; ++ct) acc[ct] = (f32x4){0.f,0.f,0.f,0.f};

  const char* bbase = (const char*)W1t;
  #pragma unroll
  for (int ct=0; ct<16; ++ct){
    const char* bp = bbase + (ct*16 + m)*256 + q*16;
    f16x8 b0 = *(const f16x8*)(bp);
    f16x8 b1 = *(const f16x8*)(bp+64);
    f16x8 b2 = *(const f16x8*)(bp+128);
    f16x8 b3 = *(const f16x8*)(bp+192);
    acc[ct] = __builtin_amdgcn_mfma_f32_16x16x32_f16(afr[0], b0, acc[ct],0,0,0);
    acc[ct] = __builtin_amdgcn_mfma_f32_16x16x32_f16(afr[1], b1, acc[ct],0,0,0);
    acc[ct] = __builtin_amdgcn_mfma_f32_16x16x32_f16(afr[2], b2, acc[ct],0,0,0);
    acc[ct] = __builtin_amdgcn_mfma_f32_16x16x32_f16(afr[3], b3, acc[ct],0,0,0);
  }
  __syncthreads();

  _Float16* Hs = (_Float16*)smem;           // [64][264] halves, 528B stride
  #pragma unroll
  for (int ct=0; ct<16; ++ct){
    #pragma unroll
    for (int r=0; r<4; ++r)
      Hs[(size_t)(r0w + q*4 + r)*264 + ct*16 + m] = (_Float16)acc[ct][r];
  }
  __syncthreads();

  for (int r=0; r<16; ++r){
    int grow = n0 + r0w + r;
    if (grow < N){
      uint2 v = *(const uint2*)((const char*)Hs + (size_t)(r0w+r)*528 + lane*8);
      *(uint2*)((char*)h1 + (size_t)grow*512 + lane*8) = v;
    }
  }

  #pragma unroll
  for (int p=t; p<512; p+=256){
    int row = p>>3, hd = p&7;
    int grow = n0 + row;
    if (grow < N){
      const f16x8* hr = (const f16x8*)((const char*)Hs + (size_t)row*528 + hd*64);
      const float* asp = as1 + hd*32;
      const float* adp = ad1 + hd*32;
      float sa=0.f, sd=0.f;
      #pragma unroll
      for (int cc=0; cc<4; ++cc){
        f16x8 hv = hr[cc];                  // ds_read_b128 (was 8 ds_read_u16)
        #pragma unroll
        for (int k=0; k<8; ++k){
          float f = (float)hv[k];
          sa += f * asp[cc*8+k];
          sd += f * adp[cc*8+k];
        }
      }
      a_src1[(size_t)grow*8+hd] = sa;
      a_dst1[(size_t)grow*8+hd] = sd;
    }
  }
}

// ---------------- K3: scatter (chunk x half, LDS u16 cursors) + rowfin finalize ----------------
__global__ __launch_bounds__(256) void k_scatter3(const int* __restrict__ srcv,
    const int* __restrict__ dstv, const int* __restrict__ rowptr,
    const unsigned short* __restrict__ pu, const int* __restrict__ bsum,
    int* __restrict__ csr_src, int* __restrict__ rowfin,
    int E, int Etot, int chunk, int SB, int N)
{
  __shared__ __align__(16) unsigned int cur[NWH];   // 50 KB
  __shared__ int bpre[64];
  int b = blockIdx.x, t = threadIdx.x;
  int c = b >> 1, half = b & 1, lo = half*HBINS;
  {
    int4* c4 = (int4*)cur;
    for (int i=t; i<NWH/4; i+=256) c4[i] = make_int4(0,0,0,0);
  }
  if (t==0){ int run=0; for (int j=0;j<SB;++j){ bpre[j]=run; run+=bsum[j]; } }
  __syncthreads();

  if (b < SB){
    int pref = bpre[b];
    int i = b*1024 + t*4;
    if (i+0 < N) rowfin[i+0] = rowptr[i+0] + pref;
    if (i+1 < N) rowfin[i+1] = rowptr[i+1] + pref;
    if (i+2 < N) rowfin[i+2] = rowptr[i+2] + pref;
    if (i+3 < N) rowfin[i+3] = rowptr[i+3] + pref;
    if (b==0 && t==0) rowfin[N] = Etot;
  }

  const unsigned short* pb = pu + (size_t)c*NBINS;
  int e0 = c*chunk, e1 = e0+chunk; if (e1 > Etot) e1 = Etot;
  int e = e0 + t;
  for (; e + 768 < e1; e += 1024){
    int ea=e, eb=e+256, ec=e+512, ed=e+768;
    int d0,s0,d1,s1,d2,s2,d3,s3;
    if (ea<E){ d0=dstv[ea]; s0=srcv[ea]; } else { d0=ea-E; s0=d0; }
    if (eb<E){ d1=dstv[eb]; s1=srcv[eb]; } else { d1=eb-E; s1=d1; }
    if (ec<E){ d2=dstv[ec]; s2=srcv[ec]; } else { d2=ec-E; s2=d2; }
    if (ed<E){ d3=dstv[ed]; s3=srcv[ed]; } else { d3=ed-E; s3=d3; }
    int r0=d0-lo, r1=d1-lo, r2=d2-lo, r3=d3-lo;
    if (r0>=0 && r0<HBINS){
      int base0 = rowptr[d0] + bpre[d0>>10] + (int)pb[d0];
      unsigned int o0 = atomicAdd(&cur[r0>>1], (r0&1)?65536u:1u);
      csr_src[base0 + ((r0&1)?(int)(o0>>16):(int)(o0&0xffff))] = s0;
    }
    if (r1>=0 && r1<HBINS){
      int base1 = rowptr[d1] + bpre[d1>>10] + (int)pb[d1];
      unsigned int o1 = atomicAdd(&cur[r1>>1], (r1&1)?65536u:1u);
      csr_src[base1 + ((r1&1)?(int)(o1>>16):(int)(o1&0xffff))] = s1;
    }
    if (r2>=0 && r2<HBINS){
      int base2 = rowptr[d2] + bpre[d2>>10] + (int)pb[d2];
      unsigned int o2 = atomicAdd(&cur[r2>>1], (r2&1)?65536u:1u);
      csr_src[base2 + ((r2&1)?(int)(o2>>16):(int)(o2&0xffff))] = s2;
    }
    if (r3>=0 && r3<HBINS){
      int base3 = rowptr[d3] + bpre[d3>>10] + (int)pb[d3];
      unsigned int o3 = atomicAdd(&cur[r3>>1], (r3&1)?65536u:1u);
      csr_src[base3 + ((r3&1)?(int)(o3>>16):(int)(o3&0xffff))] = s3;
    }
  }
  for (; e < e1; e += 256){
    int d,s;
    if (e<E){ d=dstv[e]; s=srcv[e]; } else { d=e-E; s=d; }
    int r = d - lo;
    if (r>=0 && r<HBINS){
      int base = rowptr[d] + bpre[d>>10] + (int)pb[d];
      unsigned int o = atomicAdd(&cur[r>>1], (r&1)?65536u:1u);
      csr_src[base + ((r&1)?(int)(o>>16):(int)(o&0xffff))] = s;
    }
  }
}

// ---------------- K4: Layer-1 aggregation v2 (two-phase, 16-deep scalar-addr gathers) ----------------
// CLOSED at ~73us = 94-97% of the 6.29TB/s VMEM delivery ceiling (435MB
// compulsory). Do not touch.
__global__ __launch_bounds__(256) void k_agg1(const __half* __restrict__ h1,
    const float* __restrict__ a_src1, const float* __restrict__ a_dst1,
    const int* __restrict__ rowfin, const int* __restrict__ csr_src,
    const float* __restrict__ bias1, _Float16* __restrict__ h2f, int N)
{
  __shared__ float wlds[4*640];             // 4 waves x (64 edges x 9 floats, pad)
  int wave = (blockIdx.x*blockDim.x + threadIdx.x) >> 6;
  if (wave >= N) return;
  int lane = threadIdx.x & 63;
  int wid  = (threadIdx.x >> 6) & 3;
  int head = lane >> 3;
  float* wb = wlds + wid*640;
  const float* wcol = wb + head;            // + j*9 per edge

  int beg = rowfin[wave], end = rowfin[wave+1];
  int deg = end - beg;
  const float4 av0 = *(const float4*)(a_dst1 + (size_t)wave*8);
  const float4 av1 = *(const float4*)(a_dst1 + (size_t)wave*8 + 4);

  float4 acc = make_float4(0.f,0.f,0.f,0.f);
  float wsum = 0.f;

  for (int kb = 0; kb < deg; kb += 64){
    int nb = deg - kb; if (nb > 64) nb = 64;

    // ---- phase A: per-lane edge weights for all 8 heads ----
    int sl = 0;
    if (lane < nb) sl = csr_src[beg + kb + lane];
    const float4* ep = (const float4*)(a_src1 + (size_t)sl*8);
    float4 e0 = ep[0];
    float4 e1 = ep[1];
    float w0=0.f,w1=0.f,w2=0.f,w3=0.f,w4=0.f,w5=0.f,w6=0.f,w7=0.f;
    if (lane < nb){
      w0 = __expf(lrelu(e0.x + av0.x));
      w1 = __expf(lrelu(e0.y + av0.y));
      w2 = __expf(lrelu(e0.z + av0.z));
      w3 = __expf(lrelu(e0.w + av0.w));
      w4 = __expf(lrelu(e1.x + av1.x));
      w5 = __expf(lrelu(e1.y + av1.y));
      w6 = __expf(lrelu(e1.z + av1.z));
      w7 = __expf(lrelu(e1.w + av1.w));
    }
    float* wr = wb + lane*9;
    wr[0]=w0; wr[1]=w1; wr[2]=w2; wr[3]=w3;
    wr[4]=w4; wr[5]=w5; wr[6]=w6; wr[7]=w7;
    // no barrier: region is per-wave private; same-wave DS ops are ordered.

    // ---- phase B: 16-deep gather batches ----
    int nb16 = nb & ~15;
    int j = 0;
    for (; j < nb16; j += 16){
      uint2 p[16];
      #pragma unroll
      for (int u=0;u<16;++u){
        int s = __builtin_amdgcn_readlane(sl, j+u);       // scalar row base
        p[u] = *(const uint2*)((const char*)h1 + (size_t)s*512 + lane*8);
      }
      float wv[16];
      #pragma unroll
      for (int u=0;u<16;++u) wv[u] = wcol[(j+u)*9];
      #pragma unroll
      for (int u=0;u<16;++u){
        wsum += wv[u];
        const __half2* qq = (const __half2*)&p[u];
        float2 f0 = __half22float2(qq[0]);
        float2 f1 = __half22float2(qq[1]);
        acc.x += wv[u]*f0.x; acc.y += wv[u]*f0.y;
        acc.z += wv[u]*f1.x; acc.w += wv[u]*f1.y;
      }
    }
    // remainder: padded 4-batches; padded slots have w==0 (exact no-op)
    for (; j < nb; j += 4){
      uint2 p[4]; float wv[4];
      #pragma unroll
      for (int u=0;u<4;++u){
        int jj = j+u;
        int s = __builtin_amdgcn_readlane(sl, jj & 63);
        p[u] = *(const uint2*)((const char*)h1 + (size_t)s*512 + lane*8);
        wv[u] = (jj < 64) ? wcol[jj*9] : 0.f;
      }
      #pragma unroll
      for (int u=0;u<4;++u){
        wsum += wv[u];
        const __half2* qq = (const __half2*)&p[u];
        float2 f0 = __half22float2(qq[0]);
        float2 f1 = __half22float2(qq[1]);
        acc.x += wv[u]*f0.x; acc.y += wv[u]*f0.y;
        acc.z += wv[u]*f1.x; acc.w += wv[u]*f1.y;
      }
    }
  }

  float dinv = 1.f/(wsum + 1e-16f);
  const float4 bv = *(const float4*)(bias1 + lane*4);
  float4 o;
  o.x = acc.x*dinv + bv.x;
  o.y = acc.y*dinv + bv.y;
  o.z = acc.z*dinv + bv.z;
  o.w = acc.w*dinv + bv.w;
  o.x = o.x > 0.f ? o.x : __expf(o.x)-1.f;
  o.y = o.y > 0.f ? o.y : __expf(o.y)-1.f;
  o.z = o.z > 0.f ? o.z : __expf(o.z)-1.f;
  o.w = o.w > 0.f ? o.w : __expf(o.w)-1.f;
  f16x4 ov = { (_Float16)o.x, (_Float16)o.y, (_Float16)o.z, (_Float16)o.w };
  *(f16x4*)(h2f + (size_t)wave*256 + lane*4) = ov;
}

// ---------------- K5: GEMM2 (MFMA): hb(fp16) = h2f @ W2, + a_src2/a_dst2 ----------------
__global__ __launch_bounds__(256) void k_gemm2(const _Float16* __restrict__ h2f,
    const _Float16* __restrict__ W2t, const float* __restrict__ as2, const float* __restrict__ ad2,
    _Float16* __restrict__ hbh, float* __restrict__ a_src2, float* __restrict__ a_dst2, int N)
{
  int t = threadIdx.x, wv = t>>6, lane = t&63;
  int col = lane&15, q = lane>>4;
  int n0 = blockIdx.x*64 + wv*16;
  int am = n0 + col; if (am > N-1) am = N-1;

  const _Float16* arow = h2f + (size_t)am*256 + q*8;
  const _Float16* brow = W2t + (size_t)col*256 + q*8;
  f32x4 acc = (f32x4){0.f,0.f,0.f,0.f};
  #pragma unroll
  for (int ks=0; ks<8; ++ks){
    f16x8 a = *(const f16x8*)(arow + ks*32);
    f16x8 b = *(const f16x8*)(brow + ks*32);
    acc = __builtin_amdgcn_mfma_f32_16x16x32_f16(a, b, acc, 0,0,0);
  }

  float vs = as2[col], vd = ad2[col];
  #pragma unroll
  for (int r=0; r<4; ++r){
    int n = n0 + q*4 + r;
    float v = acc[r];
    float pa = v*vs, pd = v*vd;
    #pragma unroll
    for (int msk=8; msk>=1; msk>>=1){ pa += __shfl_xor(pa,msk); pd += __shfl_xor(pd,msk); }
    if (n < N){
      hbh[(size_t)n*16 + col] = (_Float16)v;
      if (col==0){ a_src2[n] = pa; a_dst2[n] = pd; }
    }
  }
}

// ---------------- K6: Layer-2 aggregation: wave per dst, 4 edge-groups x 16 ch ----------------
__global__ __launch_bounds__(256) void k_agg2(const __half* __restrict__ hbh,
    const float* __restrict__ a_src2, const float* __restrict__ a_dst2,
    const int* __restrict__ rowfin, const int* __restrict__ csr_src,
    const float* __restrict__ bias2, float* __restrict__ out, int N)
{
  int wave = (blockIdx.x*blockDim.x + threadIdx.x) >> 6;
  if (wave >= N) return;
  int lane = threadIdx.x & 63;
  int eg   = lane >> 4;
  int ch   = lane & 15;
  float ad = a_dst2[wave];
  int beg = rowfin[wave], end = rowfin[wave+1];
  float acc = 0.f, wsum = 0.f;
  int i = beg + eg;
  for (; i+4 < end; i+=8){
    int s0 = csr_src[i], s1 = csr_src[i+4];
    float e0 = a_src2[s0], e1 = a_src2[s1];
    float h0 = __half2float(hbh[(size_t)s0*16 + ch]);
    float h1v = __half2float(hbh[(size_t)s1*16 + ch]);
    float w0 = __expf(lrelu(e0 + ad)), w1 = __expf(lrelu(e1 + ad));
    wsum += w0 + w1;
    acc += w0*h0 + w1*h1v;
  }
  for (; i<end; i+=4){
    int s = csr_src[i];
    float w = __expf(lrelu(a_src2[s] + ad));
    wsum += w;
    acc += w * __half2float(hbh[(size_t)s*16 + ch]);
  }
  acc  += __shfl_xor(acc, 16);  acc  += __shfl_xor(acc, 32);
  wsum += __shfl_xor(wsum, 16); wsum += __shfl_xor(wsum, 32);
  if (eg == 0)
    out[(size_t)wave*16 + ch] = acc/(wsum + 1e-16f) + bias2[ch];
}

extern "C" void kernel_launch(void* const* d_in, const int* in_sizes, int n_in,
                              void* d_out, int out_size, void* d_ws, size_t ws_size,
                              hipStream_t stream)
{
  const float* x   = (const float*)d_in[0];
  const int*   ei  = (const int*)  d_in[1];
  const float* W1  = (const float*)d_in[2];
  const float* as1 = (const float*)d_in[3];
  const float* ad1 = (const float*)d_in[4];
  const float* b1  = (const float*)d_in[5];
  const float* W2  = (const float*)d_in[6];
  const float* as2 = (const float*)d_in[7];
  const float* ad2 = (const float*)d_in[8];
  const float* b2  = (const float*)d_in[9];
  float* out = (float*)d_out;

  const int N    = in_sizes[0] / 128;       // 50000
  const int E    = in_sizes[1] / 2;         // 800000
  const int Etot = E + N;
  const int* srcv = ei;
  const int* dstv = ei + E;
  const int chunk = (Etot + NC - 1) / NC;   // 6641 < 65536 (u16-field safe)
  const int SB    = (N + 1023) / 1024;      // 49 scan blocks
  const int TN    = (N + 63) / 64;          // 782 gemm1 tiles

  char* p = (char*)d_ws;
  auto alloc = [&](size_t bytes)->void* {
    void* r = (void*)p;
    p += (bytes + 255) & ~((size_t)255);
    return r;
  };
  _Float16* h1   = (_Float16*)alloc((size_t)N*256*sizeof(_Float16));   // node-major [N][256]
  _Float16* W1t  = (_Float16*)alloc((size_t)256*128*sizeof(_Float16));
  _Float16* h2f  = (_Float16*)alloc((size_t)N*256*sizeof(_Float16));
  _Float16* W2t  = (_Float16*)alloc((size_t)16*256*sizeof(_Float16));
  _Float16* hbh  = (_Float16*)alloc((size_t)N*16*sizeof(_Float16));
  float* a_src1  = (float*)alloc((size_t)N*8*sizeof(float));
  float* a_dst1  = (float*)alloc((size_t)N*8*sizeof(float));
  float* a_src2  = (float*)alloc((size_t)N*sizeof(float));
  float* a_dst2  = (float*)alloc((size_t)N*sizeof(float));
  int*   rowptr  = (int*)alloc((size_t)(N+1)*sizeof(int));
  int*   rowfin  = (int*)alloc((size_t)(N+1)*sizeof(int));
  int*   bsum    = (int*)alloc(256*sizeof(int));
  unsigned int* partial = (unsigned int*)alloc((size_t)NC*HBINS*sizeof(unsigned int)); // u16[NC][50000]
  int*   csr_src = (int*)alloc((size_t)Etot*sizeof(int));

  // K1: histogram (chunk x half, 256 blocks) + weight prep
  k_histW<<<dim3(NBK+129), dim3(256), 0, stream>>>(dstv, partial, E, Etot, chunk,
                                                   W1, W1t, W2, W2t);
  // K2: scanAB (batched prefetch; blocks 0..SB-1) + gemm1 (blocks SB..SB+TN-1)
  k_g1scan<<<dim3(SB + TN), dim3(256), 0, stream>>>(x, W1t, as1, ad1, h1,
      a_src1, a_dst1, (unsigned long long*)partial, rowptr, bsum, N, SB);
  // K3: scatter + rowfin finalize
  k_scatter3<<<dim3(NBK), dim3(256), 0, stream>>>(srcv, dstv, rowptr,
      (const unsigned short*)partial, bsum, csr_src, rowfin, E, Etot, chunk, SB, N);
  // K4: agg1 (v2, closed)
  k_agg1<<<dim3((N + 3)/4), dim3(256), 0, stream>>>((const __half*)h1, a_src1, a_dst1,
      rowfin, csr_src, b1, h2f, N);
  // K5: gemm2 (fp16 hb)
  k_gemm2<<<dim3((N + 63)/64), dim3(256), 0, stream>>>(h2f, W2t, as2, ad2, hbh, a_src2, a_dst2, N);
  // K6: agg2
  k_agg2<<<dim3((N + 3)/4), dim3(256), 0, stream>>>((const __half*)hbh, a_src2, a_dst2,
      rowfin, csr_src, b2, out, N);
}